// Round 3
// baseline (1418.573 us; speedup 1.0000x reference)
//
#include <hip/hip_runtime.h>

#define N_NODES 50000
#define N_EDGES 800000
#define DD 128
#define HH 128
#define LL 4
#define AHH 16
#define LN_EPS 1e-5f
#define NCOLS 432   // 128 S | 128 P1 | 128 Pd | 16 SA | 16 P1A | 16 PdA

typedef unsigned short u16;
typedef unsigned int u32;
typedef __attribute__((ext_vector_type(8))) short short8;
typedef __attribute__((ext_vector_type(4))) float f32x4;

__device__ __forceinline__ float bf2f(u16 h){
  u32 u = ((u32)h) << 16;
  return __builtin_bit_cast(float, u);
}
__device__ __forceinline__ u16 f2bf(float x){
  u32 u = __builtin_bit_cast(u32, x);
  u += 0x7fffu + ((u >> 16) & 1u);
  return (u16)(u >> 16);
}

// ---------------- sentinel (workspace too small) ----------------
__global__ void k_fail(float* out){
  int i = blockIdx.x*256 + threadIdx.x;
  if (i < N_NODES*2) out[i] = 1.0e6f;
}

// ---------------- f32 -> bf16 conversion of node features ----------------
__global__ void k_cvt(const float* __restrict__ X, u16* __restrict__ Xb){
  int i = blockIdx.x*256 + threadIdx.x;
  if (i < N_NODES*DD) Xb[i] = f2bf(X[i]);
}

// ---------------- CSR build ----------------
__global__ void k_hist(const int* __restrict__ ei, int* degO, int* degI){
  int e = blockIdx.x*256 + threadIdx.x;
  if (e >= N_EDGES) return;
  atomicAdd(&degO[ei[N_EDGES + e]], 1);  // tgt histogram (outgoing view)
  atomicAdd(&degI[ei[e]], 1);            // src histogram (incoming view)
}

__global__ void k_scan(const int* __restrict__ degO, const int* __restrict__ degI,
                       int* offO, int* offI){
  __shared__ int sums[256];
  const int chunk = (N_NODES + 255) / 256;
  for (int pass = 0; pass < 2; ++pass){
    const int* deg = pass ? degI : degO;
    int* off = pass ? offI : offO;
    int t = threadIdx.x;
    int lo = t*chunk, hi = min(lo+chunk, N_NODES);
    int s = 0;
    for (int i = lo; i < hi; ++i) s += deg[i];
    sums[t] = s;
    __syncthreads();
    if (t == 0){
      int run = 0;
      for (int i = 0; i < 256; ++i){ int v = sums[i]; sums[i] = run; run += v; }
      off[N_NODES] = run;
    }
    __syncthreads();
    int run = sums[t];
    for (int i = lo; i < hi; ++i){ off[i] = run; run += deg[i]; }
    __syncthreads();
  }
}

__global__ void k_scatter(const int* __restrict__ ei, const int* __restrict__ offO,
                          const int* __restrict__ offI, int* cursO, int* cursI,
                          int* csrO, int* csrI){
  int e = blockIdx.x*256 + threadIdx.x;
  if (e >= N_EDGES) return;
  int s = ei[e], t = ei[N_EDGES + e];
  int p = atomicAdd(&cursO[t], 1); csrO[offO[t] + p] = s;
  int q = atomicAdd(&cursI[s], 1); csrI[offI[s] + q] = t;
}

// ---------------- weight packing (f32 sources -> bf16 WT) ----------------
__global__ void k_pack_wt(const float* __restrict__ Wself, const float* __restrict__ Wctx,
                          const float* __restrict__ A1, u16* __restrict__ WT){
  int idx = blockIdx.x*256 + threadIdx.x;
  if (idx >= LL*NCOLS*DD) return;
  int k = idx & 127;
  int j = (idx >> 7) % NCOLS;
  int l = idx / (NCOLS*DD);
  const float* Ws = Wself + (size_t)l*DD*HH;
  const float* Wc = Wctx + (size_t)l*2*DD*HH;
  const float* A  = A1 + (size_t)l*HH*AHH;
  float v = 0.f;
  if (j < 128) v = Ws[k*HH + j];
  else if (j < 256) v = Wc[k*HH + (j-128)];
  else if (j < 384) v = Wc[(128+k)*HH + (j-256)] - Wc[k*HH + (j-256)];
  else if (j < 400){ int a = j-384; for (int h=0; h<HH; ++h) v += Ws[k*HH+h] * A[h*AHH+a]; }
  else if (j < 416){ int a = j-400; for (int h=0; h<HH; ++h) v += Wc[k*HH+h] * A[h*AHH+a]; }
  else { int a = j-416; for (int h=0; h<HH; ++h) v += (Wc[(128+k)*HH+h] - Wc[k*HH+h]) * A[h*AHH+a]; }
  WT[((size_t)l*NCOLS + j)*DD + k] = f2bf(v);
}

__global__ void k_pack_bias(const float* __restrict__ bs, const float* __restrict__ bc,
                            const float* __restrict__ A1, float* bsA, float* bcA){
  int i = threadIdx.x;
  if (i >= LL*2*AHH) return;
  int l = i >> 5, which = (i >> 4) & 1, a = i & 15;
  const float* b = which ? (bc + l*HH) : (bs + l*HH);
  const float* A = A1 + (size_t)l*HH*AHH;
  float v = 0.f;
  for (int h = 0; h < HH; ++h) v += b[h] * A[h*AHH + a];
  (which ? bcA : bsA)[l*AHH + a] = v;
}

// ---------------- fused GEMM: [N,128] @ [128,432] via MFMA ----------------
struct GemmOut { u16 *S, *P1, *Pd, *SA, *P1A, *PdA; };

__global__ __launch_bounds__(256) void k_gemm(const u16* __restrict__ X,
                                              const u16* __restrict__ WT, GemmOut o){
  int wid = (blockIdx.x * 256 + threadIdx.x) >> 6;
  int lane = threadIdx.x & 63;
  int m0 = wid * 16;
  if (m0 >= N_NODES) return;
  int l15 = lane & 15, quad = lane >> 4;
  f32x4 acc[27];
  #pragma unroll
  for (int j = 0; j < 27; ++j) acc[j] = (f32x4){0.f,0.f,0.f,0.f};
  const u16* xr = X + (size_t)(m0 + l15)*DD + quad*8;
  const u16* wb = WT + (size_t)l15*DD + quad*8;
  #pragma unroll
  for (int ks = 0; ks < 4; ++ks){
    short8 a = *(const short8*)(xr + ks*32);
    #pragma unroll
    for (int j = 0; j < 27; ++j){
      short8 b = *(const short8*)(wb + (size_t)j*16*DD + ks*32);
      acc[j] = __builtin_amdgcn_mfma_f32_16x16x32_bf16(a, b, acc[j], 0, 0, 0);
    }
  }
  #pragma unroll
  for (int j = 0; j < 27; ++j){
    int col = j*16 + l15;
    #pragma unroll
    for (int r = 0; r < 4; ++r){
      int row = m0 + quad*4 + r;
      u16 hv = f2bf(acc[j][r]);
      if (col < 128)      o.S  [(size_t)row*128 + col]       = hv;
      else if (col < 256) o.P1 [(size_t)row*128 + col - 128] = hv;
      else if (col < 384) o.Pd [(size_t)row*128 + col - 256] = hv;
      else if (col < 400) o.SA [(size_t)row*16  + col - 384] = hv;
      else if (col < 416) o.P1A[(size_t)row*16  + col - 400] = hv;
      else                o.PdA[(size_t)row*16  + col - 416] = hv;
    }
  }
}

// ------- fused CSR gather + attention + LN + residual + classifier-accumulate -------
__global__ __launch_bounds__(256) void k_aggepi(int l,
  const u16* __restrict__ S, const u16* __restrict__ P1,
  const u16* __restrict__ Pd, const u16* __restrict__ SA,
  const u16* __restrict__ P1A, const u16* __restrict__ PdA,
  const int* __restrict__ offO, const int* __restrict__ offI,
  const int* __restrict__ csrO, const int* __restrict__ csrI,
  const float* __restrict__ b_self, const float* __restrict__ b_ctx,
  const float* __restrict__ bsA, const float* __restrict__ bcA,
  const float* __restrict__ att_b1, const float* __restrict__ att_w2,
  const float* __restrict__ gamma, const float* __restrict__ beta,
  const float* __restrict__ flog,
  float* __restrict__ xf, u16* __restrict__ xb16,
  const float* __restrict__ clsW, const float* __restrict__ clsB,
  float* __restrict__ out)
{
  int n = (blockIdx.x * 256 + threadIdx.x) >> 6;
  int lane = threadIdx.x & 63;
  int f0 = lane * 2;

  // outgoing view: edges with tgt==n, neighbors are sources
  int begO = offO[n], endO = offO[n+1];
  float ao0 = 0.f, ao1 = 0.f, aoa = 0.f;
  for (int e = begO; e < endO; ++e){
    int nb = csrO[e];
    u32 v = *(const u32*)(Pd + (size_t)nb*128 + f0);
    ao0 += bf2f((u16)(v & 0xffffu));
    ao1 += bf2f((u16)(v >> 16));
    if (lane < 16) aoa += bf2f(PdA[(size_t)nb*16 + lane]);
  }
  // incoming view: edges with src==n, neighbors are targets
  int begI = offI[n], endI = offI[n+1];
  float ai0 = 0.f, ai1 = 0.f, aia = 0.f;
  for (int e = begI; e < endI; ++e){
    int nb = csrI[e];
    u32 v = *(const u32*)(Pd + (size_t)nb*128 + f0);
    ai0 += bf2f((u16)(v & 0xffffu));
    ai1 += bf2f((u16)(v >> 16));
    if (lane < 16) aia += bf2f(PdA[(size_t)nb*16 + lane]);
  }
  float dO = (float)(endO - begO), dI = (float)(endI - begI);

  // three views, 2 features per lane
  u32 sv = *(const u32*)(S  + (size_t)n*128 + f0);
  u32 pv = *(const u32*)(P1 + (size_t)n*128 + f0);
  float2 bsv = *(const float2*)(b_self + l*128 + f0);
  float2 bcv = *(const float2*)(b_ctx  + l*128 + f0);
  float p10 = bf2f((u16)(pv & 0xffffu)), p11 = bf2f((u16)(pv >> 16));
  float mv00 = bf2f((u16)(sv & 0xffffu)) + bsv.x;
  float mv01 = bf2f((u16)(sv >> 16))     + bsv.y;
  float mv10 = dO*p10 + ao0 + bcv.x, mv11 = dO*p11 + ao1 + bcv.y;
  float mv20 = dI*p10 + ai0 + bcv.x, mv21 = dI*p11 + ai1 + bcv.y;

  // attention: lanes [v*16 + a], v<3 compute tanh(t + b1)*w2, reduce over a
  int a = lane & 15, v = lane >> 4;
  float aoa_b = __shfl(aoa, a);
  float aia_b = __shfl(aia, a);
  float u = 0.f;
  if (v < 3){
    float t;
    if (v == 0)      t = bf2f(SA[(size_t)n*16 + a]) + bsA[l*16 + a];
    else if (v == 1) t = dO*bf2f(P1A[(size_t)n*16 + a]) + aoa_b + bcA[l*16 + a];
    else             t = dI*bf2f(P1A[(size_t)n*16 + a]) + aia_b + bcA[l*16 + a];
    u = tanhf(t + att_b1[l*16 + a]) * att_w2[l*16 + a];
  }
  u += __shfl_xor(u, 1); u += __shfl_xor(u, 2);
  u += __shfl_xor(u, 4); u += __shfl_xor(u, 8);
  float s0 = __shfl(u, 0), s1 = __shfl(u, 16), s2 = __shfl(u, 32);
  float mx = fmaxf(s0, fmaxf(s1, s2));
  float e0 = __expf(s0-mx), e1 = __expf(s1-mx), e2 = __expf(s2-mx);
  float inv = 1.f / (e0 + e1 + e2);
  float w0 = e0*inv, w1 = e1*inv, w2v = e2*inv;
  float h0 = w0*mv00 + w1*mv10 + w2v*mv20;
  float h1 = w0*mv01 + w1*mv11 + w2v*mv21;

  // layer norm over 128
  float sum = h0 + h1, sq = h0*h0 + h1*h1;
  #pragma unroll
  for (int m = 1; m < 64; m <<= 1){ sum += __shfl_xor(sum, m); sq += __shfl_xor(sq, m); }
  float mu = sum * (1.f/128.f);
  float var = sq * (1.f/128.f) - mu*mu;
  float rs = rsqrtf(var + LN_EPS);
  float2 gv = *(const float2*)(gamma + l*128 + f0);
  float2 bv = *(const float2*)(beta  + l*128 + f0);
  float y0 = fmaxf((h0 - mu)*rs*gv.x + bv.x, 0.f);
  float y1 = fmaxf((h1 - mu)*rs*gv.y + bv.y, 0.f);
  float xn0 = y0, xn1 = y1;
  if (l > 0){
    float2 xv = *(const float2*)(xf + (size_t)n*128 + f0);
    xn0 += xv.x; xn1 += xv.y;
  }
  // write residual stream (f32) + bf16 mirror for next GEMM
  *(float2*)(xf + (size_t)n*128 + f0) = make_float2(xn0, xn1);
  *(u32*)(xb16 + (size_t)n*128 + f0) = (u32)f2bf(xn0) | ((u32)f2bf(xn1) << 16);

  // fusion weight (softmax over 4 logits)
  float g0 = flog[0], g1 = flog[1], g2 = flog[2], g3 = flog[3];
  float gm = fmaxf(fmaxf(g0,g1), fmaxf(g2,g3));
  float q0 = __expf(g0-gm), q1 = __expf(g1-gm), q2 = __expf(g2-gm), q3 = __expf(g3-gm);
  float fwl = (l==0?q0 : l==1?q1 : l==2?q2 : q3) / (q0+q1+q2+q3);

  // classifier accumulate: out[n,:] += fwl * (x_l[n] @ clsW); bias at last layer
  float4 w = *(const float4*)(clsW + lane*4);   // rows 2*lane, 2*lane+1 of [128,2]
  float o0 = xn0*w.x + xn1*w.z;
  float o1 = xn0*w.y + xn1*w.w;
  #pragma unroll
  for (int m = 1; m < 64; m <<= 1){ o0 += __shfl_xor(o0, m); o1 += __shfl_xor(o1, m); }
  if (lane == 0){
    float2* op = (float2*)(out + (size_t)n*2);
    float2 prev = (l > 0) ? *op : make_float2(0.f, 0.f);
    float r0 = prev.x + fwl*o0, r1 = prev.y + fwl*o1;
    if (l == LL-1){ r0 += clsB[0]; r1 += clsB[1]; }
    *op = make_float2(r0, r1);
  }
}

extern "C" void kernel_launch(void* const* d_in, const int* in_sizes, int n_in,
                              void* d_out, int out_size, void* d_ws, size_t ws_size,
                              hipStream_t stream){
  const float* X0    = (const float*)d_in[0];
  const int*   EI    = (const int*)d_in[1];
  const float* Wself = (const float*)d_in[2];
  const float* bs    = (const float*)d_in[3];
  const float* Wctx  = (const float*)d_in[4];
  const float* bc    = (const float*)d_in[5];
  const float* A1    = (const float*)d_in[6];
  const float* ab1   = (const float*)d_in[7];
  const float* aw2   = (const float*)d_in[8];
  const float* gam   = (const float*)d_in[9];
  const float* bet   = (const float*)d_in[10];
  const float* flog  = (const float*)d_in[11];
  const float* clsW  = (const float*)d_in[12];
  const float* clsB  = (const float*)d_in[13];
  float* out = (float*)d_out;

  char* wsp = (char*)d_ws;
  size_t o = 0;
  auto alloc = [&](size_t b)->char*{ char* p = wsp + o; o = (o + b + 255) & ~(size_t)255; return p; };
  u16*  xb16  = (u16*) alloc((size_t)N_NODES*128*2);
  float* xf   = (float*)alloc((size_t)N_NODES*128*4);
  u16*  S     = (u16*) alloc((size_t)N_NODES*128*2);
  u16*  P1    = (u16*) alloc((size_t)N_NODES*128*2);
  u16*  Pd    = (u16*) alloc((size_t)N_NODES*128*2);
  u16*  SAb   = (u16*) alloc((size_t)N_NODES*16*2);
  u16*  P1A   = (u16*) alloc((size_t)N_NODES*16*2);
  u16*  PdA   = (u16*) alloc((size_t)N_NODES*16*2);
  u16*  WT    = (u16*) alloc((size_t)LL*NCOLS*128*2);
  float* bsA  = (float*)alloc(LL*16*4);
  float* bcA  = (float*)alloc(LL*16*4);
  int* degO   = (int*) alloc((size_t)N_NODES*4);
  int* degI   = (int*) alloc((size_t)N_NODES*4);
  int* cursO  = (int*) alloc((size_t)N_NODES*4);
  int* cursI  = (int*) alloc((size_t)N_NODES*4);
  int* offO   = (int*) alloc((size_t)(N_NODES+1)*4);
  int* offI   = (int*) alloc((size_t)(N_NODES+1)*4);
  int* csrO   = (int*) alloc((size_t)N_EDGES*4);
  int* csrI   = (int*) alloc((size_t)N_EDGES*4);

  if (ws_size < o){
    // workspace too small — emit sentinel so the failure mode is identifiable
    k_fail<<<(N_NODES*2+255)/256, 256, 0, stream>>>(out);
    return;
  }

  // zero deg/cursor block (contiguous degO..cursI)
  hipMemsetAsync(degO, 0, (size_t)((char*)offO - (char*)degO), stream);

  k_cvt<<<(N_NODES*DD+255)/256, 256, 0, stream>>>(X0, xb16);
  k_hist<<<(N_EDGES+255)/256, 256, 0, stream>>>(EI, degO, degI);
  k_scan<<<1, 256, 0, stream>>>(degO, degI, offO, offI);
  k_scatter<<<(N_EDGES+255)/256, 256, 0, stream>>>(EI, offO, offI, cursO, cursI, csrO, csrI);
  k_pack_wt<<<(LL*NCOLS*128+255)/256, 256, 0, stream>>>(Wself, Wctx, A1, WT);
  k_pack_bias<<<1, 128, 0, stream>>>(bs, bc, A1, bsA, bcA);

  GemmOut go{S, P1, Pd, SAb, P1A, PdA};
  const int gemm_blocks = ((N_NODES/16) + 3) / 4;
  for (int l = 0; l < LL; ++l){
    k_gemm<<<gemm_blocks, 256, 0, stream>>>(xb16, WT + (size_t)l*NCOLS*128, go);
    k_aggepi<<<N_NODES/4, 256, 0, stream>>>(l, S, P1, Pd, SAb, P1A, PdA,
                                            offO, offI, csrO, csrI,
                                            bs, bc, bsA, bcA, ab1, aw2,
                                            gam, bet, flog, xf, xb16,
                                            clsW, clsB, out);
  }
}

// Round 4
// 1100.446 us; speedup vs baseline: 1.2891x; 1.2891x over previous
//
#include <hip/hip_runtime.h>

#define N_NODES 50000
#define N_EDGES 800000
#define DD 128
#define HH 128
#define LL 4
#define AHH 16
#define LN_EPS 1e-5f
#define NCOLS 432   // 128 S | 128 P1 | 128 Pd | 16 SA | 16 P1A | 16 PdA

typedef unsigned short u16;
typedef unsigned int u32;
typedef __attribute__((ext_vector_type(8))) short short8;
typedef __attribute__((ext_vector_type(4))) float f32x4;

__device__ __forceinline__ float bf2f(u16 h){
  u32 u = ((u32)h) << 16;
  return __builtin_bit_cast(float, u);
}
__device__ __forceinline__ float bflo(u32 v){ return __builtin_bit_cast(float, v << 16); }
__device__ __forceinline__ float bfhi(u32 v){ return __builtin_bit_cast(float, v & 0xffff0000u); }
__device__ __forceinline__ u16 f2bf(float x){
  u32 u = __builtin_bit_cast(u32, x);
  u += 0x7fffu + ((u >> 16) & 1u);
  return (u16)(u >> 16);
}

// ---------------- sentinel (workspace too small) ----------------
__global__ void k_fail(float* out){
  int i = blockIdx.x*256 + threadIdx.x;
  if (i < N_NODES*2) out[i] = 1.0e6f;
}

// ---------------- f32 -> bf16 conversion of node features ----------------
__global__ void k_cvt(const float* __restrict__ X, u16* __restrict__ Xb){
  int i = blockIdx.x*256 + threadIdx.x;
  if (i < N_NODES*DD) Xb[i] = f2bf(X[i]);
}

// ---------------- CSR build ----------------
__global__ void k_hist(const int* __restrict__ ei, int* degO, int* degI){
  int e = blockIdx.x*256 + threadIdx.x;
  if (e >= N_EDGES) return;
  atomicAdd(&degO[ei[N_EDGES + e]], 1);  // tgt histogram (outgoing view)
  atomicAdd(&degI[ei[e]], 1);            // src histogram (incoming view)
}

// tile-based parallel exclusive scan, 1024 threads, wave shfl + LDS combine
__global__ __launch_bounds__(1024) void k_scan(const int* __restrict__ degO,
                                               const int* __restrict__ degI,
                                               int* offO, int* offI){
  __shared__ int wsum[16];
  __shared__ int carry_s;
  int tid = threadIdx.x, lane = tid & 63, wid = tid >> 6;
  for (int pass = 0; pass < 2; ++pass){
    const int* deg = pass ? degI : degO;
    int* off = pass ? offI : offO;
    if (tid == 0) carry_s = 0;
    __syncthreads();
    for (int base = 0; base < N_NODES; base += 1024){
      int i = base + tid;
      int v = (i < N_NODES) ? deg[i] : 0;
      int x = v;
      #pragma unroll
      for (int s = 1; s < 64; s <<= 1){
        int t = __shfl_up(x, s);
        if (lane >= s) x += t;
      }
      if (lane == 63) wsum[wid] = x;
      __syncthreads();
      int woff = 0;
      for (int w = 0; w < wid; ++w) woff += wsum[w];
      int carry = carry_s;
      int excl = carry + woff + x - v;
      if (i < N_NODES) off[i] = excl;
      __syncthreads();
      if (tid == 1023) carry_s = excl + v;
      __syncthreads();
    }
    if (tid == 0) off[N_NODES] = carry_s;
    __syncthreads();
  }
}

__global__ void k_scatter(const int* __restrict__ ei, const int* __restrict__ offO,
                          const int* __restrict__ offI, int* cursO, int* cursI,
                          int* csrO, int* csrI){
  int e = blockIdx.x*256 + threadIdx.x;
  if (e >= N_EDGES) return;
  int s = ei[e], t = ei[N_EDGES + e];
  int p = atomicAdd(&cursO[t], 1); csrO[offO[t] + p] = s;
  int q = atomicAdd(&cursI[s], 1); csrI[offI[s] + q] = t;
}

// ---------------- weight packing (f32 sources -> bf16 WT) ----------------
__global__ void k_pack_wt(const float* __restrict__ Wself, const float* __restrict__ Wctx,
                          const float* __restrict__ A1, u16* __restrict__ WT){
  int idx = blockIdx.x*256 + threadIdx.x;
  if (idx >= LL*NCOLS*DD) return;
  int k = idx & 127;
  int j = (idx >> 7) % NCOLS;
  int l = idx / (NCOLS*DD);
  const float* Ws = Wself + (size_t)l*DD*HH;
  const float* Wc = Wctx + (size_t)l*2*DD*HH;
  const float* A  = A1 + (size_t)l*HH*AHH;
  float v = 0.f;
  if (j < 128) v = Ws[k*HH + j];
  else if (j < 256) v = Wc[k*HH + (j-128)];
  else if (j < 384) v = Wc[(128+k)*HH + (j-256)] - Wc[k*HH + (j-256)];
  else if (j < 400){ int a = j-384; for (int h=0; h<HH; ++h) v += Ws[k*HH+h] * A[h*AHH+a]; }
  else if (j < 416){ int a = j-400; for (int h=0; h<HH; ++h) v += Wc[k*HH+h] * A[h*AHH+a]; }
  else { int a = j-416; for (int h=0; h<HH; ++h) v += (Wc[(128+k)*HH+h] - Wc[k*HH+h]) * A[h*AHH+a]; }
  WT[((size_t)l*NCOLS + j)*DD + k] = f2bf(v);
}

__global__ void k_pack_bias(const float* __restrict__ bs, const float* __restrict__ bc,
                            const float* __restrict__ A1, float* bsA, float* bcA){
  int i = threadIdx.x;
  if (i >= LL*2*AHH) return;
  int l = i >> 5, which = (i >> 4) & 1, a = i & 15;
  const float* b = which ? (bc + l*HH) : (bs + l*HH);
  const float* A = A1 + (size_t)l*HH*AHH;
  float v = 0.f;
  for (int h = 0; h < HH; ++h) v += b[h] * A[h*AHH + a];
  (which ? bcA : bsA)[l*AHH + a] = v;
}

// ---------------- fused GEMM: [N,128] @ [128,432] via MFMA ----------------
struct GemmOut { u16 *S, *P1, *Pd, *SA, *P1A, *PdA; };

__global__ __launch_bounds__(256) void k_gemm(const u16* __restrict__ X,
                                              const u16* __restrict__ WT, GemmOut o){
  int wid = (blockIdx.x * 256 + threadIdx.x) >> 6;
  int lane = threadIdx.x & 63;
  int m0 = wid * 16;
  if (m0 >= N_NODES) return;
  int l15 = lane & 15, quad = lane >> 4;
  f32x4 acc[27];
  #pragma unroll
  for (int j = 0; j < 27; ++j) acc[j] = (f32x4){0.f,0.f,0.f,0.f};
  const u16* xr = X + (size_t)(m0 + l15)*DD + quad*8;
  const u16* wb = WT + (size_t)l15*DD + quad*8;
  #pragma unroll
  for (int ks = 0; ks < 4; ++ks){
    short8 a = *(const short8*)(xr + ks*32);
    #pragma unroll
    for (int j = 0; j < 27; ++j){
      short8 b = *(const short8*)(wb + (size_t)j*16*DD + ks*32);
      acc[j] = __builtin_amdgcn_mfma_f32_16x16x32_bf16(a, b, acc[j], 0, 0, 0);
    }
  }
  #pragma unroll
  for (int j = 0; j < 27; ++j){
    int col = j*16 + l15;
    #pragma unroll
    for (int r = 0; r < 4; ++r){
      int row = m0 + quad*4 + r;
      u16 hv = f2bf(acc[j][r]);
      if (col < 128)      o.S  [(size_t)row*128 + col]       = hv;
      else if (col < 256) o.P1 [(size_t)row*128 + col - 128] = hv;
      else if (col < 384) o.Pd [(size_t)row*128 + col - 256] = hv;
      else if (col < 400) o.SA [(size_t)row*16  + col - 384] = hv;
      else if (col < 416) o.P1A[(size_t)row*16  + col - 400] = hv;
      else                o.PdA[(size_t)row*16  + col - 416] = hv;
    }
  }
}

// ------- fused CSR gather + attention + LN + residual + classifier-accumulate -------
__global__ __launch_bounds__(256) void k_aggepi(int l,
  const u16* __restrict__ S, const u16* __restrict__ P1,
  const u16* __restrict__ Pd, const u16* __restrict__ SA,
  const u16* __restrict__ P1A, const u16* __restrict__ PdA,
  const int* __restrict__ offO, const int* __restrict__ offI,
  const int* __restrict__ csrO, const int* __restrict__ csrI,
  const float* __restrict__ b_self, const float* __restrict__ b_ctx,
  const float* __restrict__ bsA, const float* __restrict__ bcA,
  const float* __restrict__ att_b1, const float* __restrict__ att_w2,
  const float* __restrict__ gamma, const float* __restrict__ beta,
  const float* __restrict__ flog,
  float* __restrict__ xf, u16* __restrict__ xb16,
  const float* __restrict__ clsW, const float* __restrict__ clsB,
  float* __restrict__ out)
{
  int n = (blockIdx.x * 256 + threadIdx.x) >> 6;
  int lane = threadIdx.x & 63;
  int f0 = lane * 2;
  const u16* PdF = Pd + f0;           // per-lane column base into Pd rows

  int begO = offO[n], endO = offO[n+1];
  int begI = offI[n], endI = offI[n+1];

  // --- outgoing gather (neighbors = sources of in-edges), 4x unrolled ---
  float o00=0.f,o01=0.f,o10=0.f,o11=0.f,o20=0.f,o21=0.f,o30=0.f,o31=0.f;
  int e = begO;
  for (; e + 4 <= endO; e += 4){
    int nb0 = csrO[e], nb1 = csrO[e+1], nb2 = csrO[e+2], nb3 = csrO[e+3];
    u32 v0 = *(const u32*)(PdF + (size_t)nb0*128);
    u32 v1 = *(const u32*)(PdF + (size_t)nb1*128);
    u32 v2 = *(const u32*)(PdF + (size_t)nb2*128);
    u32 v3 = *(const u32*)(PdF + (size_t)nb3*128);
    o00 += bflo(v0); o01 += bfhi(v0);
    o10 += bflo(v1); o11 += bfhi(v1);
    o20 += bflo(v2); o21 += bfhi(v2);
    o30 += bflo(v3); o31 += bfhi(v3);
  }
  for (; e < endO; ++e){
    u32 v = *(const u32*)(PdF + (size_t)csrO[e]*128);
    o00 += bflo(v); o01 += bfhi(v);
  }
  float ao0 = (o00+o10)+(o20+o30), ao1 = (o01+o11)+(o21+o31);

  // --- incoming gather (neighbors = targets of out-edges), 4x unrolled ---
  float i00=0.f,i01=0.f,i10=0.f,i11=0.f,i20=0.f,i21=0.f,i30=0.f,i31=0.f;
  e = begI;
  for (; e + 4 <= endI; e += 4){
    int nb0 = csrI[e], nb1 = csrI[e+1], nb2 = csrI[e+2], nb3 = csrI[e+3];
    u32 v0 = *(const u32*)(PdF + (size_t)nb0*128);
    u32 v1 = *(const u32*)(PdF + (size_t)nb1*128);
    u32 v2 = *(const u32*)(PdF + (size_t)nb2*128);
    u32 v3 = *(const u32*)(PdF + (size_t)nb3*128);
    i00 += bflo(v0); i01 += bfhi(v0);
    i10 += bflo(v1); i11 += bfhi(v1);
    i20 += bflo(v2); i21 += bfhi(v2);
    i30 += bflo(v3); i31 += bfhi(v3);
  }
  for (; e < endI; ++e){
    u32 v = *(const u32*)(PdF + (size_t)csrI[e]*128);
    i00 += bflo(v); i01 += bfhi(v);
  }
  float ai0 = (i00+i10)+(i20+i30), ai1 = (i01+i11)+(i21+i31);

  // --- PdA gathers: 4 edges per iteration via the four 16-lane groups ---
  int a16 = lane & 15, g = lane >> 4;
  float aoa = 0.f, aia = 0.f;
  for (int e2 = begO + g; e2 < endO; e2 += 4)
    aoa += bf2f(PdA[(size_t)csrO[e2]*16 + a16]);
  for (int e2 = begI + g; e2 < endI; e2 += 4)
    aia += bf2f(PdA[(size_t)csrI[e2]*16 + a16]);
  aoa += __shfl_xor(aoa, 16); aoa += __shfl_xor(aoa, 32);
  aia += __shfl_xor(aia, 16); aia += __shfl_xor(aia, 32);
  // now every lane holds the full sum for feature a16 = lane & 15

  float dO = (float)(endO - begO), dI = (float)(endI - begI);

  // --- three views, 2 features per lane ---
  u32 sv = *(const u32*)(S  + (size_t)n*128 + f0);
  u32 pv = *(const u32*)(P1 + (size_t)n*128 + f0);
  float2 bsv = *(const float2*)(b_self + l*128 + f0);
  float2 bcv = *(const float2*)(b_ctx  + l*128 + f0);
  float p10 = bflo(pv), p11 = bfhi(pv);
  float mv00 = bflo(sv) + bsv.x;
  float mv01 = bfhi(sv) + bsv.y;
  float mv10 = dO*p10 + ao0 + bcv.x, mv11 = dO*p11 + ao1 + bcv.y;
  float mv20 = dI*p10 + ai0 + bcv.x, mv21 = dI*p11 + ai1 + bcv.y;

  // --- attention: lanes [v*16 + a], v<3 compute tanh(t + b1)*w2, reduce over a ---
  int a = a16, v = g;
  float u = 0.f;
  if (v < 3){
    float t;
    if (v == 0)      t = bf2f(SA[(size_t)n*16 + a]) + bsA[l*16 + a];
    else if (v == 1) t = dO*bf2f(P1A[(size_t)n*16 + a]) + aoa + bcA[l*16 + a];
    else             t = dI*bf2f(P1A[(size_t)n*16 + a]) + aia + bcA[l*16 + a];
    u = tanhf(t + att_b1[l*16 + a]) * att_w2[l*16 + a];
  }
  u += __shfl_xor(u, 1); u += __shfl_xor(u, 2);
  u += __shfl_xor(u, 4); u += __shfl_xor(u, 8);
  float s0 = __shfl(u, 0), s1 = __shfl(u, 16), s2 = __shfl(u, 32);
  float mx = fmaxf(s0, fmaxf(s1, s2));
  float e0 = __expf(s0-mx), e1 = __expf(s1-mx), e2 = __expf(s2-mx);
  float inv = 1.f / (e0 + e1 + e2);
  float w0 = e0*inv, w1 = e1*inv, w2v = e2*inv;
  float h0 = w0*mv00 + w1*mv10 + w2v*mv20;
  float h1 = w0*mv01 + w1*mv11 + w2v*mv21;

  // --- layer norm over 128 ---
  float sum = h0 + h1, sq = h0*h0 + h1*h1;
  #pragma unroll
  for (int m = 1; m < 64; m <<= 1){ sum += __shfl_xor(sum, m); sq += __shfl_xor(sq, m); }
  float mu = sum * (1.f/128.f);
  float var = sq * (1.f/128.f) - mu*mu;
  float rs = rsqrtf(var + LN_EPS);
  float2 gv = *(const float2*)(gamma + l*128 + f0);
  float2 bv = *(const float2*)(beta  + l*128 + f0);
  float y0 = fmaxf((h0 - mu)*rs*gv.x + bv.x, 0.f);
  float y1 = fmaxf((h1 - mu)*rs*gv.y + bv.y, 0.f);
  float xn0 = y0, xn1 = y1;
  if (l > 0){
    float2 xv = *(const float2*)(xf + (size_t)n*128 + f0);
    xn0 += xv.x; xn1 += xv.y;
  }
  // write residual stream (f32) + bf16 mirror for next GEMM
  *(float2*)(xf + (size_t)n*128 + f0) = make_float2(xn0, xn1);
  *(u32*)(xb16 + (size_t)n*128 + f0) = (u32)f2bf(xn0) | ((u32)f2bf(xn1) << 16);

  // fusion weight (softmax over 4 logits)
  float g0 = flog[0], g1 = flog[1], g2 = flog[2], g3 = flog[3];
  float gm = fmaxf(fmaxf(g0,g1), fmaxf(g2,g3));
  float q0 = __expf(g0-gm), q1 = __expf(g1-gm), q2 = __expf(g2-gm), q3 = __expf(g3-gm);
  float fwl = (l==0?q0 : l==1?q1 : l==2?q2 : q3) / (q0+q1+q2+q3);

  // classifier accumulate: out[n,:] += fwl * (x_l[n] @ clsW); bias at last layer
  float4 w = *(const float4*)(clsW + lane*4);   // rows 2*lane, 2*lane+1 of [128,2]
  float o0 = xn0*w.x + xn1*w.z;
  float o1 = xn0*w.y + xn1*w.w;
  #pragma unroll
  for (int m = 1; m < 64; m <<= 1){ o0 += __shfl_xor(o0, m); o1 += __shfl_xor(o1, m); }
  if (lane == 0){
    float2* op = (float2*)(out + (size_t)n*2);
    float2 prev = (l > 0) ? *op : make_float2(0.f, 0.f);
    float r0 = prev.x + fwl*o0, r1 = prev.y + fwl*o1;
    if (l == LL-1){ r0 += clsB[0]; r1 += clsB[1]; }
    *op = make_float2(r0, r1);
  }
}

extern "C" void kernel_launch(void* const* d_in, const int* in_sizes, int n_in,
                              void* d_out, int out_size, void* d_ws, size_t ws_size,
                              hipStream_t stream){
  const float* X0    = (const float*)d_in[0];
  const int*   EI    = (const int*)d_in[1];
  const float* Wself = (const float*)d_in[2];
  const float* bs    = (const float*)d_in[3];
  const float* Wctx  = (const float*)d_in[4];
  const float* bc    = (const float*)d_in[5];
  const float* A1    = (const float*)d_in[6];
  const float* ab1   = (const float*)d_in[7];
  const float* aw2   = (const float*)d_in[8];
  const float* gam   = (const float*)d_in[9];
  const float* bet   = (const float*)d_in[10];
  const float* flog  = (const float*)d_in[11];
  const float* clsW  = (const float*)d_in[12];
  const float* clsB  = (const float*)d_in[13];
  float* out = (float*)d_out;

  char* wsp = (char*)d_ws;
  size_t o = 0;
  auto alloc = [&](size_t b)->char*{ char* p = wsp + o; o = (o + b + 255) & ~(size_t)255; return p; };
  u16*  xb16  = (u16*) alloc((size_t)N_NODES*128*2);
  float* xf   = (float*)alloc((size_t)N_NODES*128*4);
  u16*  S     = (u16*) alloc((size_t)N_NODES*128*2);
  u16*  P1    = (u16*) alloc((size_t)N_NODES*128*2);
  u16*  Pd    = (u16*) alloc((size_t)N_NODES*128*2);
  u16*  SAb   = (u16*) alloc((size_t)N_NODES*16*2);
  u16*  P1A   = (u16*) alloc((size_t)N_NODES*16*2);
  u16*  PdA   = (u16*) alloc((size_t)N_NODES*16*2);
  u16*  WT    = (u16*) alloc((size_t)LL*NCOLS*128*2);
  float* bsA  = (float*)alloc(LL*16*4);
  float* bcA  = (float*)alloc(LL*16*4);
  int* degO   = (int*) alloc((size_t)N_NODES*4);
  int* degI   = (int*) alloc((size_t)N_NODES*4);
  int* cursO  = (int*) alloc((size_t)N_NODES*4);
  int* cursI  = (int*) alloc((size_t)N_NODES*4);
  int* offO   = (int*) alloc((size_t)(N_NODES+1)*4);
  int* offI   = (int*) alloc((size_t)(N_NODES+1)*4);
  int* csrO   = (int*) alloc((size_t)N_EDGES*4);
  int* csrI   = (int*) alloc((size_t)N_EDGES*4);

  if (ws_size < o){
    k_fail<<<(N_NODES*2+255)/256, 256, 0, stream>>>(out);
    return;
  }

  // zero deg/cursor block (contiguous degO..cursI)
  hipMemsetAsync(degO, 0, (size_t)((char*)offO - (char*)degO), stream);

  k_cvt<<<(N_NODES*DD+255)/256, 256, 0, stream>>>(X0, xb16);
  k_hist<<<(N_EDGES+255)/256, 256, 0, stream>>>(EI, degO, degI);
  k_scan<<<1, 1024, 0, stream>>>(degO, degI, offO, offI);
  k_scatter<<<(N_EDGES+255)/256, 256, 0, stream>>>(EI, offO, offI, cursO, cursI, csrO, csrI);
  k_pack_wt<<<(LL*NCOLS*128+255)/256, 256, 0, stream>>>(Wself, Wctx, A1, WT);
  k_pack_bias<<<1, 128, 0, stream>>>(bs, bc, A1, bsA, bcA);

  GemmOut go{S, P1, Pd, SAb, P1A, PdA};
  const int gemm_blocks = ((N_NODES/16) + 3) / 4;
  for (int l = 0; l < LL; ++l){
    k_gemm<<<gemm_blocks, 256, 0, stream>>>(xb16, WT + (size_t)l*NCOLS*128, go);
    k_aggepi<<<N_NODES/4, 256, 0, stream>>>(l, S, P1, Pd, SAb, P1A, PdA,
                                            offO, offI, csrO, csrI,
                                            bs, bc, bsA, bcA, ab1, aw2,
                                            gam, bet, flog, xf, xb16,
                                            clsW, clsB, out);
  }
}

// Round 5
// 1090.100 us; speedup vs baseline: 1.3013x; 1.0095x over previous
//
#include <hip/hip_runtime.h>

#define N_NODES 50000
#define N_EDGES 800000
#define DD 128
#define HH 128
#define LL 4
#define AHH 16
#define LN_EPS 1e-5f
#define NCOLS 432   // 128 S | 128 P1 | 128 Pd | 16 SA | 16 P1A | 16 PdA

typedef unsigned short u16;
typedef unsigned int u32;
typedef __attribute__((ext_vector_type(8))) short short8;
typedef __attribute__((ext_vector_type(4))) float f32x4;

__device__ __forceinline__ float bf2f(u16 h){
  u32 u = ((u32)h) << 16;
  return __builtin_bit_cast(float, u);
}
__device__ __forceinline__ float bflo(u32 v){ return __builtin_bit_cast(float, v << 16); }
__device__ __forceinline__ float bfhi(u32 v){ return __builtin_bit_cast(float, v & 0xffff0000u); }
__device__ __forceinline__ u16 f2bf(float x){
  u32 u = __builtin_bit_cast(u32, x);
  u += 0x7fffu + ((u >> 16) & 1u);
  return (u16)(u >> 16);
}

// ---------------- sentinel (workspace too small) ----------------
__global__ void k_fail(float* out){
  int i = blockIdx.x*256 + threadIdx.x;
  if (i < N_NODES*2) out[i] = 1.0e6f;
}

// ---------------- f32 -> bf16 conversion of node features ----------------
__global__ void k_cvt(const float* __restrict__ X, u16* __restrict__ Xb){
  int i = blockIdx.x*256 + threadIdx.x;
  if (i < N_NODES*DD) Xb[i] = f2bf(X[i]);
}

// ---------------- CSR build ----------------
__global__ void k_hist(const int* __restrict__ ei, int* degO, int* degI){
  int e = blockIdx.x*256 + threadIdx.x;
  if (e >= N_EDGES) return;
  atomicAdd(&degO[ei[N_EDGES + e]], 1);  // tgt histogram (outgoing view)
  atomicAdd(&degI[ei[e]], 1);            // src histogram (incoming view)
}

// tile-based parallel exclusive scan, 1024 threads, wave shfl + LDS combine
__global__ __launch_bounds__(1024) void k_scan(const int* __restrict__ degO,
                                               const int* __restrict__ degI,
                                               int* offO, int* offI){
  __shared__ int wsum[16];
  __shared__ int carry_s;
  int tid = threadIdx.x, lane = tid & 63, wid = tid >> 6;
  for (int pass = 0; pass < 2; ++pass){
    const int* deg = pass ? degI : degO;
    int* off = pass ? offI : offO;
    if (tid == 0) carry_s = 0;
    __syncthreads();
    for (int base = 0; base < N_NODES; base += 1024){
      int i = base + tid;
      int v = (i < N_NODES) ? deg[i] : 0;
      int x = v;
      #pragma unroll
      for (int s = 1; s < 64; s <<= 1){
        int t = __shfl_up(x, s);
        if (lane >= s) x += t;
      }
      if (lane == 63) wsum[wid] = x;
      __syncthreads();
      int woff = 0;
      for (int w = 0; w < wid; ++w) woff += wsum[w];
      int carry = carry_s;
      int excl = carry + woff + x - v;
      if (i < N_NODES) off[i] = excl;
      __syncthreads();
      if (tid == 1023) carry_s = excl + v;
      __syncthreads();
    }
    if (tid == 0) off[N_NODES] = carry_s;
    __syncthreads();
  }
}

__global__ void k_scatter(const int* __restrict__ ei, const int* __restrict__ offO,
                          const int* __restrict__ offI, int* cursO, int* cursI,
                          int* csrO, int* csrI){
  int e = blockIdx.x*256 + threadIdx.x;
  if (e >= N_EDGES) return;
  int s = ei[e], t = ei[N_EDGES + e];
  int p = atomicAdd(&cursO[t], 1); csrO[offO[t] + p] = s;
  int q = atomicAdd(&cursI[s], 1); csrI[offI[s] + q] = t;
}

// ---------------- weight packing (f32 sources -> bf16 WT) ----------------
__global__ void k_pack_wt(const float* __restrict__ Wself, const float* __restrict__ Wctx,
                          const float* __restrict__ A1, u16* __restrict__ WT){
  int idx = blockIdx.x*256 + threadIdx.x;
  if (idx >= LL*NCOLS*DD) return;
  int k = idx & 127;
  int j = (idx >> 7) % NCOLS;
  int l = idx / (NCOLS*DD);
  const float* Ws = Wself + (size_t)l*DD*HH;
  const float* Wc = Wctx + (size_t)l*2*DD*HH;
  const float* A  = A1 + (size_t)l*HH*AHH;
  float v = 0.f;
  if (j < 128) v = Ws[k*HH + j];
  else if (j < 256) v = Wc[k*HH + (j-128)];
  else if (j < 384) v = Wc[(128+k)*HH + (j-256)] - Wc[k*HH + (j-256)];
  else if (j < 400){ int a = j-384; for (int h=0; h<HH; ++h) v += Ws[k*HH+h] * A[h*AHH+a]; }
  else if (j < 416){ int a = j-400; for (int h=0; h<HH; ++h) v += Wc[k*HH+h] * A[h*AHH+a]; }
  else { int a = j-416; for (int h=0; h<HH; ++h) v += (Wc[(128+k)*HH+h] - Wc[k*HH+h]) * A[h*AHH+a]; }
  WT[((size_t)l*NCOLS + j)*DD + k] = f2bf(v);
}

__global__ void k_pack_bias(const float* __restrict__ bs, const float* __restrict__ bc,
                            const float* __restrict__ A1, float* bsA, float* bcA){
  int i = threadIdx.x;
  if (i >= LL*2*AHH) return;
  int l = i >> 5, which = (i >> 4) & 1, a = i & 15;
  const float* b = which ? (bc + l*HH) : (bs + l*HH);
  const float* A = A1 + (size_t)l*HH*AHH;
  float v = 0.f;
  for (int h = 0; h < HH; ++h) v += b[h] * A[h*AHH + a];
  (which ? bcA : bsA)[l*AHH + a] = v;
}

// ---------------- fused GEMM: [N,128] @ [128,432] via MFMA ----------------
struct GemmOut { u16 *S, *P1, *Pd, *SA, *P1A, *PdA; };

__global__ __launch_bounds__(256) void k_gemm(const u16* __restrict__ X,
                                              const u16* __restrict__ WT, GemmOut o){
  int wid = (blockIdx.x * 256 + threadIdx.x) >> 6;
  int lane = threadIdx.x & 63;
  int m0 = wid * 16;
  if (m0 >= N_NODES) return;
  int l15 = lane & 15, quad = lane >> 4;
  f32x4 acc[27];
  #pragma unroll
  for (int j = 0; j < 27; ++j) acc[j] = (f32x4){0.f,0.f,0.f,0.f};
  const u16* xr = X + (size_t)(m0 + l15)*DD + quad*8;
  const u16* wb = WT + (size_t)l15*DD + quad*8;
  #pragma unroll
  for (int ks = 0; ks < 4; ++ks){
    short8 a = *(const short8*)(xr + ks*32);
    #pragma unroll
    for (int j = 0; j < 27; ++j){
      short8 b = *(const short8*)(wb + (size_t)j*16*DD + ks*32);
      acc[j] = __builtin_amdgcn_mfma_f32_16x16x32_bf16(a, b, acc[j], 0, 0, 0);
    }
  }
  #pragma unroll
  for (int j = 0; j < 27; ++j){
    int col = j*16 + l15;
    #pragma unroll
    for (int r = 0; r < 4; ++r){
      int row = m0 + quad*4 + r;
      u16 hv = f2bf(acc[j][r]);
      if (col < 128)      o.S  [(size_t)row*128 + col]       = hv;
      else if (col < 256) o.P1 [(size_t)row*128 + col - 128] = hv;
      else if (col < 384) o.Pd [(size_t)row*128 + col - 256] = hv;
      else if (col < 400) o.SA [(size_t)row*16  + col - 384] = hv;
      else if (col < 416) o.P1A[(size_t)row*16  + col - 400] = hv;
      else                o.PdA[(size_t)row*16  + col - 416] = hv;
    }
  }
}

// ------- fused CSR gather + attention + LN + residual + classifier-accumulate -------
__global__ __launch_bounds__(256) void k_aggepi(int l,
  const u16* __restrict__ S, const u16* __restrict__ P1,
  const u16* __restrict__ Pd, const u16* __restrict__ SA,
  const u16* __restrict__ P1A, const u16* __restrict__ PdA,
  const int* __restrict__ offO, const int* __restrict__ offI,
  const int* __restrict__ csrO, const int* __restrict__ csrI,
  const float* __restrict__ b_self, const float* __restrict__ b_ctx,
  const float* __restrict__ bsA, const float* __restrict__ bcA,
  const float* __restrict__ att_b1, const float* __restrict__ att_w2,
  const float* __restrict__ gamma, const float* __restrict__ beta,
  const float* __restrict__ flog,
  float* __restrict__ xf, u16* __restrict__ xb16,
  const float* __restrict__ clsW, const float* __restrict__ clsB,
  float* __restrict__ out)
{
  int n = (blockIdx.x * 256 + threadIdx.x) >> 6;
  int lane = threadIdx.x & 63;
  int f0 = lane * 2;
  const u16* PdF = Pd + f0;           // per-lane column base into Pd rows

  int begO = offO[n], endO = offO[n+1];
  int begI = offI[n], endI = offI[n+1];

  float o00=0.f,o01=0.f,o10=0.f,o11=0.f,o20=0.f,o21=0.f,o30=0.f,o31=0.f;
  float i00=0.f,i01=0.f,i10=0.f,i11=0.f,i20=0.f,i21=0.f,i30=0.f,i31=0.f;

  int eO = begO, eI = begI;
  // scalar alignment heads: make eO/eI multiples of 4 (csr bases are 256B-aligned)
  for (; eO < endO && (eO & 3); ++eO){
    u32 v = *(const u32*)(PdF + (size_t)csrO[eO]*128);
    o00 += bflo(v); o01 += bfhi(v);
  }
  for (; eI < endI && (eI & 3); ++eI){
    u32 v = *(const u32*)(PdF + (size_t)csrI[eI]*128);
    i00 += bflo(v); i01 += bfhi(v);
  }
  // fused main loop: 4 outgoing + 4 incoming gathers in flight, int4 index loads
  for (; eO + 4 <= endO && eI + 4 <= endI; eO += 4, eI += 4){
    int4 nO = *(const int4*)(csrO + eO);
    int4 nI = *(const int4*)(csrI + eI);
    u32 a0 = *(const u32*)(PdF + (size_t)nO.x*128);
    u32 a1 = *(const u32*)(PdF + (size_t)nO.y*128);
    u32 a2 = *(const u32*)(PdF + (size_t)nO.z*128);
    u32 a3 = *(const u32*)(PdF + (size_t)nO.w*128);
    u32 b0 = *(const u32*)(PdF + (size_t)nI.x*128);
    u32 b1 = *(const u32*)(PdF + (size_t)nI.y*128);
    u32 b2 = *(const u32*)(PdF + (size_t)nI.z*128);
    u32 b3 = *(const u32*)(PdF + (size_t)nI.w*128);
    o00 += bflo(a0); o01 += bfhi(a0);
    o10 += bflo(a1); o11 += bfhi(a1);
    o20 += bflo(a2); o21 += bfhi(a2);
    o30 += bflo(a3); o31 += bfhi(a3);
    i00 += bflo(b0); i01 += bfhi(b0);
    i10 += bflo(b1); i11 += bfhi(b1);
    i20 += bflo(b2); i21 += bfhi(b2);
    i30 += bflo(b3); i31 += bfhi(b3);
  }
  // drain outgoing
  for (; eO + 4 <= endO; eO += 4){
    int4 nO = *(const int4*)(csrO + eO);
    u32 a0 = *(const u32*)(PdF + (size_t)nO.x*128);
    u32 a1 = *(const u32*)(PdF + (size_t)nO.y*128);
    u32 a2 = *(const u32*)(PdF + (size_t)nO.z*128);
    u32 a3 = *(const u32*)(PdF + (size_t)nO.w*128);
    o00 += bflo(a0); o01 += bfhi(a0);
    o10 += bflo(a1); o11 += bfhi(a1);
    o20 += bflo(a2); o21 += bfhi(a2);
    o30 += bflo(a3); o31 += bfhi(a3);
  }
  for (; eO < endO; ++eO){
    u32 v = *(const u32*)(PdF + (size_t)csrO[eO]*128);
    o00 += bflo(v); o01 += bfhi(v);
  }
  // drain incoming
  for (; eI + 4 <= endI; eI += 4){
    int4 nI = *(const int4*)(csrI + eI);
    u32 b0 = *(const u32*)(PdF + (size_t)nI.x*128);
    u32 b1 = *(const u32*)(PdF + (size_t)nI.y*128);
    u32 b2 = *(const u32*)(PdF + (size_t)nI.z*128);
    u32 b3 = *(const u32*)(PdF + (size_t)nI.w*128);
    i00 += bflo(b0); i01 += bfhi(b0);
    i10 += bflo(b1); i11 += bfhi(b1);
    i20 += bflo(b2); i21 += bfhi(b2);
    i30 += bflo(b3); i31 += bfhi(b3);
  }
  for (; eI < endI; ++eI){
    u32 v = *(const u32*)(PdF + (size_t)csrI[eI]*128);
    i00 += bflo(v); i01 += bfhi(v);
  }
  float ao0 = (o00+o10)+(o20+o30), ao1 = (o01+o11)+(o21+o31);
  float ai0 = (i00+i10)+(i20+i30), ai1 = (i01+i11)+(i21+i31);

  // --- PdA gathers: 4 edges per iteration via the four 16-lane groups ---
  int a16 = lane & 15, g = lane >> 4;
  float aoa = 0.f, aia = 0.f;
  for (int e2 = begO + g; e2 < endO; e2 += 4)
    aoa += bf2f(PdA[(size_t)csrO[e2]*16 + a16]);
  for (int e2 = begI + g; e2 < endI; e2 += 4)
    aia += bf2f(PdA[(size_t)csrI[e2]*16 + a16]);
  aoa += __shfl_xor(aoa, 16); aoa += __shfl_xor(aoa, 32);
  aia += __shfl_xor(aia, 16); aia += __shfl_xor(aia, 32);
  // now every lane holds the full sum for feature a16 = lane & 15

  float dO = (float)(endO - begO), dI = (float)(endI - begI);

  // --- three views, 2 features per lane ---
  u32 sv = *(const u32*)(S  + (size_t)n*128 + f0);
  u32 pv = *(const u32*)(P1 + (size_t)n*128 + f0);
  float2 bsv = *(const float2*)(b_self + l*128 + f0);
  float2 bcv = *(const float2*)(b_ctx  + l*128 + f0);
  float p10 = bflo(pv), p11 = bfhi(pv);
  float mv00 = bflo(sv) + bsv.x;
  float mv01 = bfhi(sv) + bsv.y;
  float mv10 = dO*p10 + ao0 + bcv.x, mv11 = dO*p11 + ao1 + bcv.y;
  float mv20 = dI*p10 + ai0 + bcv.x, mv21 = dI*p11 + ai1 + bcv.y;

  // --- attention: lanes [v*16 + a], v<3 compute tanh(t + b1)*w2, reduce over a ---
  int a = a16, v = g;
  float u = 0.f;
  if (v < 3){
    float t;
    if (v == 0)      t = bf2f(SA[(size_t)n*16 + a]) + bsA[l*16 + a];
    else if (v == 1) t = dO*bf2f(P1A[(size_t)n*16 + a]) + aoa + bcA[l*16 + a];
    else             t = dI*bf2f(P1A[(size_t)n*16 + a]) + aia + bcA[l*16 + a];
    u = tanhf(t + att_b1[l*16 + a]) * att_w2[l*16 + a];
  }
  u += __shfl_xor(u, 1); u += __shfl_xor(u, 2);
  u += __shfl_xor(u, 4); u += __shfl_xor(u, 8);
  float s0 = __shfl(u, 0), s1 = __shfl(u, 16), s2 = __shfl(u, 32);
  float mx = fmaxf(s0, fmaxf(s1, s2));
  float e0 = __expf(s0-mx), e1 = __expf(s1-mx), e2 = __expf(s2-mx);
  float inv = 1.f / (e0 + e1 + e2);
  float w0 = e0*inv, w1 = e1*inv, w2v = e2*inv;
  float h0 = w0*mv00 + w1*mv10 + w2v*mv20;
  float h1 = w0*mv01 + w1*mv11 + w2v*mv21;

  // --- layer norm over 128 ---
  float sum = h0 + h1, sq = h0*h0 + h1*h1;
  #pragma unroll
  for (int m = 1; m < 64; m <<= 1){ sum += __shfl_xor(sum, m); sq += __shfl_xor(sq, m); }
  float mu = sum * (1.f/128.f);
  float var = sq * (1.f/128.f) - mu*mu;
  float rs = rsqrtf(var + LN_EPS);
  float2 gv = *(const float2*)(gamma + l*128 + f0);
  float2 bv = *(const float2*)(beta  + l*128 + f0);
  float y0 = fmaxf((h0 - mu)*rs*gv.x + bv.x, 0.f);
  float y1 = fmaxf((h1 - mu)*rs*gv.y + bv.y, 0.f);
  float xn0 = y0, xn1 = y1;
  if (l > 0){
    float2 xv = *(const float2*)(xf + (size_t)n*128 + f0);
    xn0 += xv.x; xn1 += xv.y;
  }
  // write residual stream (f32) + bf16 mirror for next GEMM
  *(float2*)(xf + (size_t)n*128 + f0) = make_float2(xn0, xn1);
  *(u32*)(xb16 + (size_t)n*128 + f0) = (u32)f2bf(xn0) | ((u32)f2bf(xn1) << 16);

  // fusion weight (softmax over 4 logits)
  float g0 = flog[0], g1 = flog[1], g2 = flog[2], g3 = flog[3];
  float gm = fmaxf(fmaxf(g0,g1), fmaxf(g2,g3));
  float q0 = __expf(g0-gm), q1 = __expf(g1-gm), q2 = __expf(g2-gm), q3 = __expf(g3-gm);
  float fwl = (l==0?q0 : l==1?q1 : l==2?q2 : q3) / (q0+q1+q2+q3);

  // classifier accumulate: out[n,:] += fwl * (x_l[n] @ clsW); bias at last layer
  float4 w = *(const float4*)(clsW + lane*4);   // rows 2*lane, 2*lane+1 of [128,2]
  float o0 = xn0*w.x + xn1*w.z;
  float o1 = xn0*w.y + xn1*w.w;
  #pragma unroll
  for (int m = 1; m < 64; m <<= 1){ o0 += __shfl_xor(o0, m); o1 += __shfl_xor(o1, m); }
  if (lane == 0){
    float2* op = (float2*)(out + (size_t)n*2);
    float2 prev = (l > 0) ? *op : make_float2(0.f, 0.f);
    float r0 = prev.x + fwl*o0, r1 = prev.y + fwl*o1;
    if (l == LL-1){ r0 += clsB[0]; r1 += clsB[1]; }
    *op = make_float2(r0, r1);
  }
}

extern "C" void kernel_launch(void* const* d_in, const int* in_sizes, int n_in,
                              void* d_out, int out_size, void* d_ws, size_t ws_size,
                              hipStream_t stream){
  const float* X0    = (const float*)d_in[0];
  const int*   EI    = (const int*)d_in[1];
  const float* Wself = (const float*)d_in[2];
  const float* bs    = (const float*)d_in[3];
  const float* Wctx  = (const float*)d_in[4];
  const float* bc    = (const float*)d_in[5];
  const float* A1    = (const float*)d_in[6];
  const float* ab1   = (const float*)d_in[7];
  const float* aw2   = (const float*)d_in[8];
  const float* gam   = (const float*)d_in[9];
  const float* bet   = (const float*)d_in[10];
  const float* flog  = (const float*)d_in[11];
  const float* clsW  = (const float*)d_in[12];
  const float* clsB  = (const float*)d_in[13];
  float* out = (float*)d_out;

  char* wsp = (char*)d_ws;
  size_t o = 0;
  auto alloc = [&](size_t b)->char*{ char* p = wsp + o; o = (o + b + 255) & ~(size_t)255; return p; };
  u16*  xb16  = (u16*) alloc((size_t)N_NODES*128*2);
  float* xf   = (float*)alloc((size_t)N_NODES*128*4);
  u16*  S     = (u16*) alloc((size_t)N_NODES*128*2);
  u16*  P1    = (u16*) alloc((size_t)N_NODES*128*2);
  u16*  Pd    = (u16*) alloc((size_t)N_NODES*128*2);
  u16*  SAb   = (u16*) alloc((size_t)N_NODES*16*2);
  u16*  P1A   = (u16*) alloc((size_t)N_NODES*16*2);
  u16*  PdA   = (u16*) alloc((size_t)N_NODES*16*2);
  u16*  WT    = (u16*) alloc((size_t)LL*NCOLS*128*2);
  float* bsA  = (float*)alloc(LL*16*4);
  float* bcA  = (float*)alloc(LL*16*4);
  int* degO   = (int*) alloc((size_t)N_NODES*4);
  int* degI   = (int*) alloc((size_t)N_NODES*4);
  int* cursO  = (int*) alloc((size_t)N_NODES*4);
  int* cursI  = (int*) alloc((size_t)N_NODES*4);
  int* offO   = (int*) alloc((size_t)(N_NODES+1)*4);
  int* offI   = (int*) alloc((size_t)(N_NODES+1)*4);
  int* csrO   = (int*) alloc((size_t)N_EDGES*4);
  int* csrI   = (int*) alloc((size_t)N_EDGES*4);

  if (ws_size < o){
    k_fail<<<(N_NODES*2+255)/256, 256, 0, stream>>>(out);
    return;
  }

  // zero deg/cursor block (contiguous degO..cursI)
  hipMemsetAsync(degO, 0, (size_t)((char*)offO - (char*)degO), stream);

  k_cvt<<<(N_NODES*DD+255)/256, 256, 0, stream>>>(X0, xb16);
  k_hist<<<(N_EDGES+255)/256, 256, 0, stream>>>(EI, degO, degI);
  k_scan<<<1, 1024, 0, stream>>>(degO, degI, offO, offI);
  k_scatter<<<(N_EDGES+255)/256, 256, 0, stream>>>(EI, offO, offI, cursO, cursI, csrO, csrI);
  k_pack_wt<<<(LL*NCOLS*128+255)/256, 256, 0, stream>>>(Wself, Wctx, A1, WT);
  k_pack_bias<<<1, 128, 0, stream>>>(bs, bc, A1, bsA, bcA);

  GemmOut go{S, P1, Pd, SAb, P1A, PdA};
  const int gemm_blocks = ((N_NODES/16) + 3) / 4;
  for (int l = 0; l < LL; ++l){
    k_gemm<<<gemm_blocks, 256, 0, stream>>>(xb16, WT + (size_t)l*NCOLS*128, go);
    k_aggepi<<<N_NODES/4, 256, 0, stream>>>(l, S, P1, Pd, SAb, P1A, PdA,
                                            offO, offI, csrO, csrI,
                                            bs, bc, bsA, bcA, ab1, aw2,
                                            gam, bet, flog, xf, xb16,
                                            clsW, clsB, out);
  }
}